// Round 18
// baseline (133.728 us; speedup 1.0000x reference)
//
#include <hip/hip_runtime.h>

#define Bq 8
#define Sq 256
#define Hq 100
#define Pq 20
#define PPq 21
#define Fq 105
#define EPSq 1e-8f
#define NEGB -1e30f
#define IMG (128 * 136)   // padded bf16 operand image: 128 rows x 136 shorts (272 B)

typedef short bf16x8 __attribute__((ext_vector_type(8)));
typedef float f32x4 __attribute__((ext_vector_type(4)));

__device__ __forceinline__ unsigned fkey(float f) {
    unsigned b = __float_as_uint(f);
    return (b & 0x80000000u) ? ~b : (b | 0x80000000u);
}
__device__ __forceinline__ float funkey(unsigned k) {
    return __uint_as_float((k & 0x80000000u) ? (k ^ 0x80000000u) : ~k);
}
__device__ __forceinline__ unsigned short bf16rn(float f) {
    unsigned u = __float_as_uint(f);
    unsigned r = u + 0x7FFFu + ((u >> 16) & 1u);
    return (unsigned short)(r >> 16);
}
__device__ __forceinline__ unsigned mulpack(unsigned pair, float w0, float w1) {
    float f0 = __uint_as_float(pair << 16);
    float f1 = __uint_as_float(pair & 0xFFFF0000u);
    f0 *= w0; f1 *= w1;
    return ((unsigned)bf16rn(f0)) | (((unsigned)bf16rn(f1)) << 16);
}

// ---------------- k_prep: 256 blocks = (side, b, 16-token sixteenth) ----------------------
__global__ __launch_bounds__(256) void k_prep(
    const float* __restrict__ ctx_p, const int* __restrict__ mask_p,
    const float* __restrict__ ctx_h, const int* __restrict__ mask_h,
    const float* __restrict__ w_mp,
    float* __restrict__ vm, float* __restrict__ vmT,
    float* __restrict__ mf, float* __restrict__ wn,
    unsigned short* __restrict__ a16,   // [2 side][B][2 half][IMG]
    float* __restrict__ lens, int* __restrict__ lasts,
    unsigned* __restrict__ statinit) {  // 4*B*PP*S words to zero
    __shared__ float tileT[Hq * 17];    // [h][s_local 16], stride-17 pad
    __shared__ float w2T[Hq * 20];      // [h][p]
    __shared__ float redp[PPq * 4 * 16];// [p][hq][sl]
    __shared__ float smf[16];
    __shared__ int ired[256];
    int blk = blockIdx.x;
    int side = blk >> 7;
    int b = (blk >> 4) & 7;
    int sq = blk & 15;
    int s0 = sq * 16;
    int t = threadIdx.x;

    for (int idx = blk * 256 + t; idx < 4 * Bq * PPq * Sq; idx += 256 * 256)
        statinit[idx] = 0u;

    const float* ctx = side ? ctx_h : ctx_p;
    const int* mask = side ? mask_h : mask_p;
    ired[t] = mask[b * Sq + t];
    if (t < 16) smf[t] = (float)mask[b * Sq + s0 + t];
    for (int idx = t; idx < Pq * Hq; idx += 256) {
        int p = idx / Hq, h = idx - p * Hq;
        float w = w_mp[idx];
        w2T[h * 20 + p] = w * w;
    }
    __syncthreads();
    if (sq == 0) {                      // block-uniform branch: syncthreads legal
        for (int o = 128; o; o >>= 1) {
            if (t < o) ired[t] += ired[t + o];
            __syncthreads();
        }
        if (t == 0) {
            int l = ired[0];
            lens[side * Bq + b] = (float)l;
            lasts[side * Bq + b] = l > 0 ? l - 1 : 0;
        }
    }

    unsigned short* abase = a16 + (size_t)(side * Bq + b) * 2 * IMG;
    // zero pad region h in [100,136) for this block's 16 rows
    {
        ushort4 z = {0, 0, 0, 0};
        for (int idx = t; idx < 144; idx += 256) {
            int r = idx / 9, c = idx - r * 9;
            int g = s0 + r;
            *(ushort4*)(abase + (g >> 7) * IMG + (g & 127) * 136 + 100 + c * 4) = z;
        }
    }

    const float4* src = (const float4*)(ctx + ((size_t)b * Sq + s0) * Hq);
    float4* vmo = (float4*)(vm + ((size_t)side * Bq + b) * Sq * Hq + (size_t)s0 * Hq);
#pragma unroll
    for (int q = 0; q < 2; q++) {
        int F = t + 256 * q;
        if (F < 400) {                  // 16 rows x 25 float4
            int s = F / 25, c = F - s * 25;
            float m = smf[s];
            float4 v4 = src[F];
            v4.x *= m; v4.y *= m; v4.z *= m; v4.w *= m;
            vmo[F] = v4;
            int h0 = c * 4;
            tileT[(h0 + 0) * 17 + s] = v4.x;
            tileT[(h0 + 1) * 17 + s] = v4.y;
            tileT[(h0 + 2) * 17 + s] = v4.z;
            tileT[(h0 + 3) * 17 + s] = v4.w;
            int g = s0 + s;
            ushort4 o;
            o.x = bf16rn(v4.x); o.y = bf16rn(v4.y); o.z = bf16rn(v4.z); o.w = bf16rn(v4.w);
            *(ushort4*)(abase + (g >> 7) * IMG + (g & 127) * 136 + c * 4) = o;
        }
    }
    __syncthreads();

    if (t < 64) {                       // 16 tokens x 4 h-groups of 25 (order as before)
        int sl = t & 15, hq = t >> 4;
        float acc[PPq];
#pragma unroll
        for (int p = 0; p < PPq; p++) acc[p] = 0.f;
        float* vmTo = vmT + ((size_t)side * Bq + b) * Hq * Sq + s0;
        int hbeg = hq * 25;
#pragma unroll 5
        for (int h = hbeg; h < hbeg + 25; h++) {
            float v = tileT[h * 17 + sl];
            vmTo[(size_t)h * Sq + sl] = v;
            float e = v * v;
            acc[Pq] += e;
            const float4* wrow = (const float4*)(w2T + h * 20);
#pragma unroll
            for (int pq = 0; pq < 5; pq++) {
                float4 w4 = wrow[pq];
                acc[pq * 4 + 0] += w4.x * e;
                acc[pq * 4 + 1] += w4.y * e;
                acc[pq * 4 + 2] += w4.z * e;
                acc[pq * 4 + 3] += w4.w * e;
            }
        }
#pragma unroll
        for (int p = 0; p < PPq; p++)
            redp[(p * 4 + hq) * 16 + sl] = acc[p];
    }
    __syncthreads();

    float* wout = wn + ((size_t)side * Bq + b) * PPq * Sq + s0;
    for (int idx = t; idx < PPq * 16; idx += 256) {
        int p = idx >> 4, s2 = idx & 15;
        float ssum = redp[(p * 4 + 0) * 16 + s2] + redp[(p * 4 + 1) * 16 + s2] +
                     redp[(p * 4 + 2) * 16 + s2] + redp[(p * 4 + 3) * 16 + s2];
        wout[p * Sq + s2] = 1.f / fmaxf(sqrtf(ssum), EPSq);
    }
    if (t < 16) mf[(size_t)side * Bq * Sq + b * Sq + s0 + t] = smf[t];
}

// ---------------- k_pw: blocks 0..63 = exact-f32 plain cosine (runs first);
//   blocks 64..703 = bf16 MFMA weighted perspectives.
//   R8: A-fragments read DIRECTLY from global a16 (L2-hot, 40x reuse) — A LDS staging
//   deleted; B staged once for both K-chunks -> 1 barrier/block instead of 4. ------------
__global__ __launch_bounds__(256) void k_pw(
    const unsigned short* __restrict__ a16,
    const float* __restrict__ vmT,
    const float* __restrict__ wn, const float* __restrict__ mf,
    const float* __restrict__ w_mp, const float* __restrict__ lens,
    float* __restrict__ out, float* __restrict__ cosm, float* __restrict__ cosT,
    unsigned* __restrict__ rowmax, float* __restrict__ rowsum,
    unsigned* __restrict__ colmax, float* __restrict__ colsum) {
    __shared__ unsigned short Bs[2 * 128 * 72]; // [q][j][h-chunk] bf16 of w^2*b (36.9 KB)
    __shared__ float w2s[144];
    int blk = blockIdx.x;
    int t = threadIdx.x;

    if (blk >= 64) {
        // ---------------- MFMA path ----------------
        int mblk = blk - 64;
        int b = mblk / 80;
        int rem = mblk - b * 80;
        int p = rem >> 2;
        int ih = (rem >> 1) & 1, jh = rem & 1;
        int i0 = ih * 128, j0 = jh * 128;

        if (t < 144) {
            float w = (t < Hq) ? w_mp[p * Hq + t] : 0.f;
            w2s[t] = w * w;
        }
        __syncthreads();

        const unsigned short* ag = a16 + (size_t)(b * 2 + ih) * IMG;     // A half-image
        const uint4* sb = (const uint4*)(a16 + (size_t)((Bq + b) * 2 + jh) * IMG);
        uint4* dB = (uint4*)Bs;

        int lane = t & 63;
        int wv = t >> 6;
        int wr = wv & 1, wc = wv >> 1;
        int lm = lane & 15, lq = lane >> 4;

        f32x4 acc[4][4];
#pragma unroll
        for (int tm = 0; tm < 4; tm++)
#pragma unroll
            for (int tn = 0; tn < 4; tn++) acc[tm][tn] = 0.f;

        // stage BOTH B K-chunks (2048 uint4), one barrier total
#pragma unroll
        for (int it = 0; it < 8; it++) {
            int idx = t + 256 * it;              // 0..2047
            int q = idx >> 10, rem2 = idx & 1023;
            int row = rem2 >> 3, cc = rem2 & 7;
            int hb = (q * 8 + cc) * 8;
            uint4 ch = sb[row * 17 + q * 8 + cc];
            float4 wA = *(const float4*)(w2s + hb);
            float4 wB = *(const float4*)(w2s + hb + 4);
            uint4 o;
            o.x = mulpack(ch.x, wA.x, wA.y);
            o.y = mulpack(ch.y, wA.z, wA.w);
            o.z = mulpack(ch.z, wB.x, wB.y);
            o.w = mulpack(ch.w, wB.z, wB.w);
            dB[q * 1152 + row * 9 + cc] = o;
        }
        __syncthreads();

#pragma unroll
        for (int q = 0; q < 2; q++)
#pragma unroll
            for (int ksl = 0; ksl < 2; ksl++) {
                bf16x8 af[4], bfr[4];
#pragma unroll
                for (int tm = 0; tm < 4; tm++)
                    af[tm] = *(const bf16x8*)&ag[(wr * 64 + tm * 16 + lm) * 136 + q * 64 + ksl * 32 + lq * 8];
#pragma unroll
                for (int tn = 0; tn < 4; tn++)
                    bfr[tn] = *(const bf16x8*)&Bs[q * 9216 + (wc * 64 + tn * 16 + lm) * 72 + ksl * 32 + lq * 8];
#pragma unroll
                for (int tm = 0; tm < 4; tm++)
#pragma unroll
                    for (int tn = 0; tn < 4; tn++)
                        acc[tm][tn] = __builtin_amdgcn_mfma_f32_16x16x32_bf16(af[tm], bfr[tn], acc[tm][tn], 0, 0, 0);
            }

        const float* wn0 = wn + ((size_t)b * PPq + p) * Sq;
        const float* wn1 = wn + ((size_t)(Bq + b) * PPq + p) * Sq;
        const float* mfp = mf + b * Sq;
        const float* mfh = mf + (size_t)Bq * Sq + b * Sq;
        size_t base = ((size_t)b * PPq + p) * Sq;
        float rn2v[4], mzh[4];
#pragma unroll
        for (int tn = 0; tn < 4; tn++) {
            int jj = j0 + wc * 64 + tn * 16 + lm;
            rn2v[tn] = wn1[jj];
            mzh[tn] = mfh[jj] > 0.5f ? 0.f : NEGB;
        }
        float cmax[4] = {NEGB, NEGB, NEGB, NEGB};
        float csum[4] = {0.f, 0.f, 0.f, 0.f};
#pragma unroll
        for (int tm = 0; tm < 4; tm++) {
            int ibase = i0 + wr * 64 + tm * 16 + lq * 4;
            float rn1v[4], mzp[4];
#pragma unroll
            for (int r2 = 0; r2 < 4; r2++) {
                rn1v[r2] = wn0[ibase + r2];
                mzp[r2] = mfp[ibase + r2] > 0.5f ? 0.f : NEGB;
            }
            float rmax[4] = {NEGB, NEGB, NEGB, NEGB};
            float rsum[4] = {0.f, 0.f, 0.f, 0.f};
#pragma unroll
            for (int tn = 0; tn < 4; tn++)
#pragma unroll
                for (int r2 = 0; r2 < 4; r2++) {
                    float v = acc[tm][tn][r2] * rn1v[r2] * rn2v[tn];
                    rmax[r2] = fmaxf(rmax[r2], v + mzh[tn]);
                    rsum[r2] += v;
                    cmax[tn] = fmaxf(cmax[tn], v + mzp[r2]);
                    csum[tn] += v;
                }
#pragma unroll
            for (int r2 = 0; r2 < 4; r2++)
#pragma unroll
                for (int o = 1; o < 16; o <<= 1) {
                    rmax[r2] = fmaxf(rmax[r2], __shfl_xor(rmax[r2], o, 64));
                    rsum[r2] += __shfl_xor(rsum[r2], o, 64);
                }
            if (lm == 0) {
#pragma unroll
                for (int r2 = 0; r2 < 4; r2++) {
                    atomicMax(rowmax + base + ibase + r2, fkey(rmax[r2]));
                    atomicAdd(rowsum + base + ibase + r2, rsum[r2]);
                }
            }
        }
#pragma unroll
        for (int tn = 0; tn < 4; tn++) {
#pragma unroll
            for (int o = 16; o < 64; o <<= 1) {
                cmax[tn] = fmaxf(cmax[tn], __shfl_xor(cmax[tn], o, 64));
                csum[tn] += __shfl_xor(csum[tn], o, 64);
            }
        }
        if (lq == 0) {
#pragma unroll
            for (int tn = 0; tn < 4; tn++) {
                int jj = j0 + wc * 64 + tn * 16 + lm;
                atomicMax(colmax + base + jj, fkey(cmax[tn]));
                atomicAdd(colsum + base + jj, csum[tn]);
            }
        }
        return;
    }

    // ---------------- exact-f32 plain cosine path (p == 20), blocks 0..63 ----------------
    float (*cbmax)[Sq] = (float (*)[Sq])Bs;             // 0..4 KB of Bs
    float (*cbsum)[Sq] = (float (*)[Sq])(Bs + 4096);    // 8..12 KB of Bs (within 36.9 KB)
    int b = blk >> 3, it = blk & 7;
    int lane = t & 63;
    int wid = __builtin_amdgcn_readfirstlane(t >> 6);
    int i0 = it * 32 + wid * 8;

    const float* abase2 = vmT + (size_t)b * Hq * Sq;
    const float* bbase2 = vmT + (size_t)(Bq + b) * Hq * Sq;

    float4 acc[8];
#pragma unroll
    for (int k = 0; k < 8; k++) acc[k] = make_float4(0.f, 0.f, 0.f, 0.f);

#pragma unroll 4
    for (int h = 0; h < Hq; h++) {
        float4 bq = ((const float4*)(bbase2 + h * Sq))[lane];
        const float4* ap = (const float4*)(abase2 + h * Sq + i0);
        float4 a0 = ap[0], a1 = ap[1];
        float av[8] = {a0.x, a0.y, a0.z, a0.w, a1.x, a1.y, a1.z, a1.w};
#pragma unroll
        for (int k = 0; k < 8; k++) {
            acc[k].x += av[k] * bq.x; acc[k].y += av[k] * bq.y;
            acc[k].z += av[k] * bq.z; acc[k].w += av[k] * bq.w;
        }
    }

    const float* wn0 = wn + ((size_t)b * PPq + Pq) * Sq;
    const float* wn1 = wn + ((size_t)(Bq + b) * PPq + Pq) * Sq;
    float4 rn2 = ((const float4*)wn1)[lane];
    float4 mh4 = ((const float4*)(mf + (size_t)Bq * Sq + b * Sq))[lane];
    float invLh = 1.f / fmaxf(lens[Bq + b], EPSq);

    float cmax[4] = {NEGB, NEGB, NEGB, NEGB};
    float csum[4] = {0.f, 0.f, 0.f, 0.f};
#pragma unroll
    for (int k = 0; k < 8; k++) {
        float r1 = wn0[i0 + k];
        float4 v;
        v.x = acc[k].x * r1 * rn2.x;
        v.y = acc[k].y * r1 * rn2.y;
        v.z = acc[k].z * r1 * rn2.z;
        v.w = acc[k].w * r1 * rn2.w;
        float m0 = mh4.x > 0.5f ? v.x : NEGB;
        float m1 = mh4.y > 0.5f ? v.y : NEGB;
        float m2 = mh4.z > 0.5f ? v.z : NEGB;
        float m3 = mh4.w > 0.5f ? v.w : NEGB;
        float rmax = fmaxf(fmaxf(m0, m1), fmaxf(m2, m3));
        float rs = v.x + v.y + v.z + v.w;
        for (int o = 32; o; o >>= 1) {
            rmax = fmaxf(rmax, __shfl_xor(rmax, o, 64));
            rs += __shfl_xor(rs, o, 64);
        }
        if (lane == 0) {
            float* orow = out + ((size_t)(b * Sq + i0 + k)) * Fq;
            orow[0] = rmax;
            orow[1] = rs * invLh;
        }
        float mi = mf[b * Sq + i0 + k];
        if (mi > 0.5f) {
            cmax[0] = fmaxf(cmax[0], v.x); cmax[1] = fmaxf(cmax[1], v.y);
            cmax[2] = fmaxf(cmax[2], v.z); cmax[3] = fmaxf(cmax[3], v.w);
        }
        csum[0] += v.x; csum[1] += v.y; csum[2] += v.z; csum[3] += v.w;
        ((float4*)(cosm + (size_t)(b * Sq + i0 + k) * Sq))[lane] = v;
        int jb = 4 * lane;
        cosT[((size_t)b * Sq + jb + 0) * Sq + i0 + k] = v.x;
        cosT[((size_t)b * Sq + jb + 1) * Sq + i0 + k] = v.y;
        cosT[((size_t)b * Sq + jb + 2) * Sq + i0 + k] = v.z;
        cosT[((size_t)b * Sq + jb + 3) * Sq + i0 + k] = v.w;
    }
    ((float4*)&cbmax[wid][0])[lane] = make_float4(cmax[0], cmax[1], cmax[2], cmax[3]);
    ((float4*)&cbsum[wid][0])[lane] = make_float4(csum[0], csum[1], csum[2], csum[3]);
    __syncthreads();
    {
        int j = t;
        float mx = fmaxf(fmaxf(cbmax[0][j], cbmax[1][j]), fmaxf(cbmax[2][j], cbmax[3][j]));
        float sm = cbsum[0][j] + cbsum[1][j] + cbsum[2][j] + cbsum[3][j];
        size_t cidx = ((size_t)b * PPq + Pq) * Sq + j;
        atomicMax(colmax + cidx, fkey(mx));
        atomicAdd(colsum + cidx, sm);
    }
}

// ---------------- k_attf: k_att + fused k_final --------------------------------------------
// R13: Lw2 LDS table (25.2 KB) deleted — final phase recomputes w*w from the L1-resident
// global weight tables (bit-identical arithmetic). LDS ~61 KB -> ~35.4 KB => occupancy
// 2 -> 4 blocks/CU, doubling latency hiding for the cos-row staging and kk main loop.
// grid 512 = (2 dir) x (8 b) x (32 row-tiles of 8 rows), 256 threads
__global__ __launch_bounds__(256) void k_attf(
    const float* __restrict__ vm, const float* __restrict__ mf,
    const float* __restrict__ cosm, const float* __restrict__ cosT,
    const unsigned* __restrict__ rowmax, const float* __restrict__ rowsum,
    const unsigned* __restrict__ colmax, const float* __restrict__ colsum,
    const float* __restrict__ lens, const int* __restrict__ lasts,
    const float* __restrict__ w_full, const float* __restrict__ w_att,
    const float* __restrict__ w_maxatt,
    float* __restrict__ out) {
    __shared__ float L[Sq * 8];          // [k][8 r]
    __shared__ float bm[Sq];
    __shared__ float pam[2][8][128];
    __shared__ float pax[2][8][128];
    __shared__ float Lv1[8 * 104];       // [r][h]  masked context rows (side d)
    __shared__ float Lam[8 * 104];       // [r][h]  attention-mean vectors
    __shared__ float Lax[8 * 104];       // [r][h]  attention-max  vectors
    __shared__ float Lv2u[104];          // last valid token of other side
    int blk = blockIdx.x;
    int t = threadIdx.x;
    int d = blk >> 8;
    int rem = blk & 255;
    int b = rem >> 5, rt = rem & 31;
    int r0 = rt * 8;

    if (blk < Bq * PPq) {            // col fold -> dir1 rows
        int bcf = blk / PPq, pcf = blk - bcf * PPq;
        float mx = funkey(colmax[(size_t)blk * Sq + t]);
        float sm = colsum[(size_t)blk * Sq + t];
        float invLp = 1.f / fmaxf(lens[bcf], EPSq);
        float* orow = out + (size_t)Bq * Sq * Fq + (size_t)(bcf * Sq + t) * Fq;
        if (pcf < Pq) { orow[23 + pcf] = mx; orow[43 + pcf] = sm * invLp; }
        else { orow[0] = mx; orow[1] = sm * invLp; }
    } else if (blk < 2 * Bq * PPq) { // row fold -> dir0 rows (p<20; p==20 by cos path)
        int rf = blk - Bq * PPq;
        int bcf = rf / PPq, pcf = rf - bcf * PPq;
        if (pcf < Pq) {
            float mx = funkey(rowmax[(size_t)(bcf * PPq + pcf) * Sq + t]);
            float sm = rowsum[(size_t)(bcf * PPq + pcf) * Sq + t];
            float invLh = 1.f / fmaxf(lens[Bq + bcf], EPSq);
            float* orow = out + (size_t)(bcf * Sq + t) * Fq;
            orow[23 + pcf] = mx; orow[43 + pcf] = sm * invLh;
        }
    }
    bm[t] = (mf[(size_t)(1 - d) * Bq * Sq + b * Sq + t] > 0.5f) ? 0.f : NEGB;

    // --- prologue loads for the fused final phase (independent, overlap with L staging) ---
    for (int idx = t; idx < 8 * Hq; idx += 256) {
        int r = idx / Hq, h = idx - r * Hq;
        Lv1[r * 104 + h] =
            vm[(size_t)d * Bq * Sq * Hq + ((size_t)b * Sq + r0 + r) * Hq + h];
    }
    if (t < Hq) {
        int lastO = d ? lasts[b] : lasts[Bq + b];
        Lv2u[t] = vm[(size_t)(1 - d) * Bq * Sq * Hq + ((size_t)b * Sq + lastO) * Hq + t];
    }

    const float* src = (d ? cosm : cosT) + (size_t)b * Sq * Sq;
#pragma unroll
    for (int q = 0; q < 2; q++) {
        int F = t + 256 * q;
        int k = F >> 1, c = F & 1;
        float4 v4 = *(const float4*)(src + (size_t)k * Sq + r0 + c * 4);
        *(float4*)(L + k * 8 + c * 4) = v4;
    }
    __syncthreads();

    int h = t & 127, kh = t >> 7;
    const float* vB = vm + (size_t)(1 - d) * Bq * Sq * Hq + (size_t)b * Sq * Hq + h;
    bool hv = (h < Hq);
    float am[8], ax[8];
#pragma unroll
    for (int r = 0; r < 8; r++) { am[r] = 0.f; ax[r] = NEGB; }
    int k0 = kh * 128;
#pragma unroll 16
    for (int kk = 0; kk < 128; kk++) {
        int k = k0 + kk;
        float v = hv ? vB[(size_t)k * Hq] : 0.f;
        float4 w0 = *(const float4*)(L + k * 8);
        float4 w1 = *(const float4*)(L + k * 8 + 4);
        float bk = bm[k];
        float wv[8] = {w0.x, w0.y, w0.z, w0.w, w1.x, w1.y, w1.z, w1.w};
#pragma unroll
        for (int r = 0; r < 8; r++) {
            float pr = wv[r] * v;
            am[r] += pr;
            ax[r] = fmaxf(ax[r], pr + bk);
        }
    }
#pragma unroll
    for (int r = 0; r < 8; r++) { pam[kh][r][h] = am[r]; pax[kh][r][h] = ax[r]; }
    __syncthreads();
    if (t < Hq) {
#pragma unroll
        for (int r = 0; r < 8; r++) {
            Lam[r * 104 + t] = pam[0][r][t] + pam[1][r][t];
            Lax[r * 104 + t] = fmaxf(pax[0][r][t], pax[1][r][t]);
        }
    }
    __syncthreads();

    // --- fused k_final phase: 504 tasks = 8 rows x 3 matchers x 21 (20 persp + plain) ---
    // R13: weights read from global (L1-hot 8 KB tables), squared inline — identical values
    // to the old Lw2 entries. p==20 (plain cosine) uses w=1; clamped pointer avoids OOB.
    size_t orow_base = (size_t)d * Bq * Sq * Fq + ((size_t)b * Sq + r0) * Fq;
    for (int task = t; task < 504; task += 256) {
        int r = task & 7;
        int mp = task >> 3;              // 0..62
        int m = mp / 21, p = mp - m * 21;
        const float* v1p = Lv1 + r * 104;
        const float* v2p = (m == 0) ? Lv2u : (m == 1 ? Lam + r * 104 : Lax + r * 104);
        bool pw = (p < Pq);
        const float* Wg = ((m == 0) ? w_full : (m == 1) ? w_att : w_maxatt)
                          + (pw ? p : 0) * Hq;
        float dd = 0.f, aa = 0.f, bb = 0.f;
#pragma unroll 4
        for (int hh = 0; hh < Hq; hh++) {
            float v1 = v1p[hh], v2 = v2p[hh];
            float wv = pw ? Wg[hh] : 1.f;
            float w = wv * wv;
            dd += w * v1 * v2; aa += w * v1 * v1; bb += w * v2 * v2;
        }
        int fbase = (m == 0) ? 2 : (m == 1) ? 63 : 84;
        int col = (p < 20) ? (fbase + 1 + p) : fbase;
        out[orow_base + (size_t)r * Fq + col] =
            dd / (fmaxf(sqrtf(aa), EPSq) * fmaxf(sqrtf(bb), EPSq));
    }
}

extern "C" void kernel_launch(void* const* d_in, const int* in_sizes, int n_in,
                              void* d_out, int out_size, void* d_ws, size_t ws_size,
                              hipStream_t stream) {
    (void)in_sizes; (void)n_in; (void)out_size; (void)ws_size;
    const float* ctx_p    = (const float*)d_in[0];
    const int*   mask_p   = (const int*)d_in[1];
    const float* ctx_h    = (const float*)d_in[2];
    const int*   mask_h   = (const int*)d_in[3];
    const float* w_full   = (const float*)d_in[4];
    const float* w_maxpool= (const float*)d_in[5];
    const float* w_att    = (const float*)d_in[6];
    const float* w_maxatt = (const float*)d_in[7];
    float* out = (float*)d_out;
    float* ws = (float*)d_ws;

    const size_t BSH = (size_t)Bq * Sq * Hq;
    const size_t BS  = (size_t)Bq * Sq;
    const size_t BSS = (size_t)Bq * Sq * Sq;
    const size_t BPS = (size_t)Bq * PPq * Sq;

    float* vm     = ws;               ws += 2 * BSH;
    float* vmT    = ws;               ws += 2 * BSH;
    unsigned short* a16 = (unsigned short*)ws;  ws += 2 * Bq * IMG / 2 * 2;  // 2*8*2*IMG shorts
    float* mf     = ws;               ws += 2 * BS;
    float* wn     = ws;               ws += 2 * BPS;
    float* cosm   = ws;               ws += BSS;
    float* cosT   = ws;               ws += BSS;
    unsigned* rowmax = (unsigned*)ws; ws += BPS;
    float* rowsum = ws;               ws += BPS;
    unsigned* colmax = (unsigned*)ws; ws += BPS;
    float* colsum = ws;               ws += BPS;   // row/col stat bufs contiguous (one zero pass)
    float* lens   = ws;               ws += 16;
    int*   lasts  = (int*)ws;         ws += 16;

    k_prep<<<256, 256, 0, stream>>>(ctx_p, mask_p, ctx_h, mask_h, w_maxpool,
                                    vm, vmT, mf, wn, a16, lens, lasts, rowmax);
    k_pw<<<704, 256, 0, stream>>>(a16, vmT, wn, mf, w_maxpool, lens,
                                  out, cosm, cosT, rowmax, rowsum, colmax, colsum);
    k_attf<<<512, 256, 0, stream>>>(vm, mf, cosm, cosT, rowmax, rowsum, colmax, colsum,
                                    lens, lasts, w_full, w_att, w_maxatt, out);
}

// Round 19
// 128.803 us; speedup vs baseline: 1.0382x; 1.0382x over previous
//
#include <hip/hip_runtime.h>

#define Bq 8
#define Sq 256
#define Hq 100
#define Pq 20
#define PPq 21
#define Fq 105
#define EPSq 1e-8f
#define NEGB -1e30f
#define IMG (128 * 136)   // padded bf16 operand image: 128 rows x 136 shorts (272 B)

typedef short bf16x8 __attribute__((ext_vector_type(8)));
typedef float f32x4 __attribute__((ext_vector_type(4)));

__device__ __forceinline__ unsigned fkey(float f) {
    unsigned b = __float_as_uint(f);
    return (b & 0x80000000u) ? ~b : (b | 0x80000000u);
}
__device__ __forceinline__ float funkey(unsigned k) {
    return __uint_as_float((k & 0x80000000u) ? (k ^ 0x80000000u) : ~k);
}
__device__ __forceinline__ unsigned short bf16rn(float f) {
    unsigned u = __float_as_uint(f);
    unsigned r = u + 0x7FFFu + ((u >> 16) & 1u);
    return (unsigned short)(r >> 16);
}
__device__ __forceinline__ unsigned mulpack(unsigned pair, float w0, float w1) {
    float f0 = __uint_as_float(pair << 16);
    float f1 = __uint_as_float(pair & 0xFFFF0000u);
    f0 *= w0; f1 *= w1;
    return ((unsigned)bf16rn(f0)) | (((unsigned)bf16rn(f1)) << 16);
}

// ---------------- k_prep: 256 blocks = (side, b, 16-token sixteenth) ----------------------
__global__ __launch_bounds__(256) void k_prep(
    const float* __restrict__ ctx_p, const int* __restrict__ mask_p,
    const float* __restrict__ ctx_h, const int* __restrict__ mask_h,
    const float* __restrict__ w_mp,
    float* __restrict__ vm, float* __restrict__ vmT,
    float* __restrict__ mf, float* __restrict__ wn,
    unsigned short* __restrict__ a16,   // [2 side][B][2 half][IMG]
    float* __restrict__ lens, int* __restrict__ lasts,
    unsigned* __restrict__ statinit) {  // 4*B*PP*S words to zero
    __shared__ float tileT[Hq * 17];    // [h][s_local 16], stride-17 pad
    __shared__ float w2T[Hq * 20];      // [h][p]
    __shared__ float redp[PPq * 4 * 16];// [p][hq][sl]
    __shared__ float smf[16];
    __shared__ int ired[256];
    int blk = blockIdx.x;
    int side = blk >> 7;
    int b = (blk >> 4) & 7;
    int sq = blk & 15;
    int s0 = sq * 16;
    int t = threadIdx.x;

    for (int idx = blk * 256 + t; idx < 4 * Bq * PPq * Sq; idx += 256 * 256)
        statinit[idx] = 0u;

    const float* ctx = side ? ctx_h : ctx_p;
    const int* mask = side ? mask_h : mask_p;
    ired[t] = mask[b * Sq + t];
    if (t < 16) smf[t] = (float)mask[b * Sq + s0 + t];
    for (int idx = t; idx < Pq * Hq; idx += 256) {
        int p = idx / Hq, h = idx - p * Hq;
        float w = w_mp[idx];
        w2T[h * 20 + p] = w * w;
    }
    __syncthreads();
    if (sq == 0) {                      // block-uniform branch: syncthreads legal
        for (int o = 128; o; o >>= 1) {
            if (t < o) ired[t] += ired[t + o];
            __syncthreads();
        }
        if (t == 0) {
            int l = ired[0];
            lens[side * Bq + b] = (float)l;
            lasts[side * Bq + b] = l > 0 ? l - 1 : 0;
        }
    }

    unsigned short* abase = a16 + (size_t)(side * Bq + b) * 2 * IMG;
    // zero pad region h in [100,136) for this block's 16 rows
    {
        ushort4 z = {0, 0, 0, 0};
        for (int idx = t; idx < 144; idx += 256) {
            int r = idx / 9, c = idx - r * 9;
            int g = s0 + r;
            *(ushort4*)(abase + (g >> 7) * IMG + (g & 127) * 136 + 100 + c * 4) = z;
        }
    }

    const float4* src = (const float4*)(ctx + ((size_t)b * Sq + s0) * Hq);
    float4* vmo = (float4*)(vm + ((size_t)side * Bq + b) * Sq * Hq + (size_t)s0 * Hq);
#pragma unroll
    for (int q = 0; q < 2; q++) {
        int F = t + 256 * q;
        if (F < 400) {                  // 16 rows x 25 float4
            int s = F / 25, c = F - s * 25;
            float m = smf[s];
            float4 v4 = src[F];
            v4.x *= m; v4.y *= m; v4.z *= m; v4.w *= m;
            vmo[F] = v4;
            int h0 = c * 4;
            tileT[(h0 + 0) * 17 + s] = v4.x;
            tileT[(h0 + 1) * 17 + s] = v4.y;
            tileT[(h0 + 2) * 17 + s] = v4.z;
            tileT[(h0 + 3) * 17 + s] = v4.w;
            int g = s0 + s;
            ushort4 o;
            o.x = bf16rn(v4.x); o.y = bf16rn(v4.y); o.z = bf16rn(v4.z); o.w = bf16rn(v4.w);
            *(ushort4*)(abase + (g >> 7) * IMG + (g & 127) * 136 + c * 4) = o;
        }
    }
    __syncthreads();

    if (t < 64) {                       // 16 tokens x 4 h-groups of 25 (order as before)
        int sl = t & 15, hq = t >> 4;
        float acc[PPq];
#pragma unroll
        for (int p = 0; p < PPq; p++) acc[p] = 0.f;
        float* vmTo = vmT + ((size_t)side * Bq + b) * Hq * Sq + s0;
        int hbeg = hq * 25;
#pragma unroll 5
        for (int h = hbeg; h < hbeg + 25; h++) {
            float v = tileT[h * 17 + sl];
            vmTo[(size_t)h * Sq + sl] = v;
            float e = v * v;
            acc[Pq] += e;
            const float4* wrow = (const float4*)(w2T + h * 20);
#pragma unroll
            for (int pq = 0; pq < 5; pq++) {
                float4 w4 = wrow[pq];
                acc[pq * 4 + 0] += w4.x * e;
                acc[pq * 4 + 1] += w4.y * e;
                acc[pq * 4 + 2] += w4.z * e;
                acc[pq * 4 + 3] += w4.w * e;
            }
        }
#pragma unroll
        for (int p = 0; p < PPq; p++)
            redp[(p * 4 + hq) * 16 + sl] = acc[p];
    }
    __syncthreads();

    float* wout = wn + ((size_t)side * Bq + b) * PPq * Sq + s0;
    for (int idx = t; idx < PPq * 16; idx += 256) {
        int p = idx >> 4, s2 = idx & 15;
        float ssum = redp[(p * 4 + 0) * 16 + s2] + redp[(p * 4 + 1) * 16 + s2] +
                     redp[(p * 4 + 2) * 16 + s2] + redp[(p * 4 + 3) * 16 + s2];
        wout[p * Sq + s2] = 1.f / fmaxf(sqrtf(ssum), EPSq);
    }
    if (t < 16) mf[(size_t)side * Bq * Sq + b * Sq + s0 + t] = smf[t];
}

// ---------------- k_pw: blocks 0..255 = exact-f32 plain cosine (R18: widened 64->256,
//   8 rows/block, 2 rows/wave -> 4x TLP to hide L2 latency);
//   blocks 256..895 = bf16 MFMA weighted perspectives (R8 structure, unchanged). ----------
__global__ __launch_bounds__(256) void k_pw(
    const unsigned short* __restrict__ a16,
    const float* __restrict__ vmT,
    const float* __restrict__ wn, const float* __restrict__ mf,
    const float* __restrict__ w_mp, const float* __restrict__ lens,
    float* __restrict__ out, float* __restrict__ cosm, float* __restrict__ cosT,
    unsigned* __restrict__ rowmax, float* __restrict__ rowsum,
    unsigned* __restrict__ colmax, float* __restrict__ colsum) {
    __shared__ unsigned short Bs[2 * 128 * 72]; // [q][j][h-chunk] bf16 of w^2*b (36.9 KB)
    __shared__ float w2s[144];
    int blk = blockIdx.x;
    int t = threadIdx.x;

    if (blk >= 256) {
        // ---------------- MFMA path ----------------
        int mblk = blk - 256;
        int b = mblk / 80;
        int rem = mblk - b * 80;
        int p = rem >> 2;
        int ih = (rem >> 1) & 1, jh = rem & 1;
        int i0 = ih * 128, j0 = jh * 128;

        if (t < 144) {
            float w = (t < Hq) ? w_mp[p * Hq + t] : 0.f;
            w2s[t] = w * w;
        }
        __syncthreads();

        const unsigned short* ag = a16 + (size_t)(b * 2 + ih) * IMG;     // A half-image
        const uint4* sb = (const uint4*)(a16 + (size_t)((Bq + b) * 2 + jh) * IMG);
        uint4* dB = (uint4*)Bs;

        int lane = t & 63;
        int wv = t >> 6;
        int wr = wv & 1, wc = wv >> 1;
        int lm = lane & 15, lq = lane >> 4;

        f32x4 acc[4][4];
#pragma unroll
        for (int tm = 0; tm < 4; tm++)
#pragma unroll
            for (int tn = 0; tn < 4; tn++) acc[tm][tn] = 0.f;

        // stage BOTH B K-chunks (2048 uint4), one barrier total
#pragma unroll
        for (int it = 0; it < 8; it++) {
            int idx = t + 256 * it;              // 0..2047
            int q = idx >> 10, rem2 = idx & 1023;
            int row = rem2 >> 3, cc = rem2 & 7;
            int hb = (q * 8 + cc) * 8;
            uint4 ch = sb[row * 17 + q * 8 + cc];
            float4 wA = *(const float4*)(w2s + hb);
            float4 wB = *(const float4*)(w2s + hb + 4);
            uint4 o;
            o.x = mulpack(ch.x, wA.x, wA.y);
            o.y = mulpack(ch.y, wA.z, wA.w);
            o.z = mulpack(ch.z, wB.x, wB.y);
            o.w = mulpack(ch.w, wB.z, wB.w);
            dB[q * 1152 + row * 9 + cc] = o;
        }
        __syncthreads();

#pragma unroll
        for (int q = 0; q < 2; q++)
#pragma unroll
            for (int ksl = 0; ksl < 2; ksl++) {
                bf16x8 af[4], bfr[4];
#pragma unroll
                for (int tm = 0; tm < 4; tm++)
                    af[tm] = *(const bf16x8*)&ag[(wr * 64 + tm * 16 + lm) * 136 + q * 64 + ksl * 32 + lq * 8];
#pragma unroll
                for (int tn = 0; tn < 4; tn++)
                    bfr[tn] = *(const bf16x8*)&Bs[q * 9216 + (wc * 64 + tn * 16 + lm) * 72 + ksl * 32 + lq * 8];
#pragma unroll
                for (int tm = 0; tm < 4; tm++)
#pragma unroll
                    for (int tn = 0; tn < 4; tn++)
                        acc[tm][tn] = __builtin_amdgcn_mfma_f32_16x16x32_bf16(af[tm], bfr[tn], acc[tm][tn], 0, 0, 0);
            }

        const float* wn0 = wn + ((size_t)b * PPq + p) * Sq;
        const float* wn1 = wn + ((size_t)(Bq + b) * PPq + p) * Sq;
        const float* mfp = mf + b * Sq;
        const float* mfh = mf + (size_t)Bq * Sq + b * Sq;
        size_t base = ((size_t)b * PPq + p) * Sq;
        float rn2v[4], mzh[4];
#pragma unroll
        for (int tn = 0; tn < 4; tn++) {
            int jj = j0 + wc * 64 + tn * 16 + lm;
            rn2v[tn] = wn1[jj];
            mzh[tn] = mfh[jj] > 0.5f ? 0.f : NEGB;
        }
        float cmax[4] = {NEGB, NEGB, NEGB, NEGB};
        float csum[4] = {0.f, 0.f, 0.f, 0.f};
#pragma unroll
        for (int tm = 0; tm < 4; tm++) {
            int ibase = i0 + wr * 64 + tm * 16 + lq * 4;
            float rn1v[4], mzp[4];
#pragma unroll
            for (int r2 = 0; r2 < 4; r2++) {
                rn1v[r2] = wn0[ibase + r2];
                mzp[r2] = mfp[ibase + r2] > 0.5f ? 0.f : NEGB;
            }
            float rmax[4] = {NEGB, NEGB, NEGB, NEGB};
            float rsum[4] = {0.f, 0.f, 0.f, 0.f};
#pragma unroll
            for (int tn = 0; tn < 4; tn++)
#pragma unroll
                for (int r2 = 0; r2 < 4; r2++) {
                    float v = acc[tm][tn][r2] * rn1v[r2] * rn2v[tn];
                    rmax[r2] = fmaxf(rmax[r2], v + mzh[tn]);
                    rsum[r2] += v;
                    cmax[tn] = fmaxf(cmax[tn], v + mzp[r2]);
                    csum[tn] += v;
                }
#pragma unroll
            for (int r2 = 0; r2 < 4; r2++)
#pragma unroll
                for (int o = 1; o < 16; o <<= 1) {
                    rmax[r2] = fmaxf(rmax[r2], __shfl_xor(rmax[r2], o, 64));
                    rsum[r2] += __shfl_xor(rsum[r2], o, 64);
                }
            if (lm == 0) {
#pragma unroll
                for (int r2 = 0; r2 < 4; r2++) {
                    atomicMax(rowmax + base + ibase + r2, fkey(rmax[r2]));
                    atomicAdd(rowsum + base + ibase + r2, rsum[r2]);
                }
            }
        }
#pragma unroll
        for (int tn = 0; tn < 4; tn++) {
#pragma unroll
            for (int o = 16; o < 64; o <<= 1) {
                cmax[tn] = fmaxf(cmax[tn], __shfl_xor(cmax[tn], o, 64));
                csum[tn] += __shfl_xor(csum[tn], o, 64);
            }
        }
        if (lq == 0) {
#pragma unroll
            for (int tn = 0; tn < 4; tn++) {
                int jj = j0 + wc * 64 + tn * 16 + lm;
                atomicMax(colmax + base + jj, fkey(cmax[tn]));
                atomicAdd(colsum + base + jj, csum[tn]);
            }
        }
        return;
    }

    // ------- exact-f32 plain cosine path (p == 20), blocks 0..255 (R18 widened) ----------
    // 8 rows/block (2 rows/wave): 4x more waves than the old 64-block layout, hiding the
    // per-iteration L2 load latency that made this path the kernel's critical-path tail.
    float (*cbmax)[Sq] = (float (*)[Sq])Bs;             // 0..4 KB of Bs
    float (*cbsum)[Sq] = (float (*)[Sq])(Bs + 4096);    // 8..12 KB of Bs (within 36.9 KB)
    int b = blk >> 5, it = blk & 31;
    int lane = t & 63;
    int wid = __builtin_amdgcn_readfirstlane(t >> 6);
    int i0 = it * 8 + wid * 2;

    const float* abase2 = vmT + (size_t)b * Hq * Sq;
    const float* bbase2 = vmT + (size_t)(Bq + b) * Hq * Sq;

    float4 acc[2];
#pragma unroll
    for (int k = 0; k < 2; k++) acc[k] = make_float4(0.f, 0.f, 0.f, 0.f);

#pragma unroll 4
    for (int h = 0; h < Hq; h++) {
        float4 bq = ((const float4*)(bbase2 + h * Sq))[lane];
        float2 a01 = *(const float2*)(abase2 + h * Sq + i0);
        float av[2] = {a01.x, a01.y};
#pragma unroll
        for (int k = 0; k < 2; k++) {
            acc[k].x += av[k] * bq.x; acc[k].y += av[k] * bq.y;
            acc[k].z += av[k] * bq.z; acc[k].w += av[k] * bq.w;
        }
    }

    const float* wn0 = wn + ((size_t)b * PPq + Pq) * Sq;
    const float* wn1 = wn + ((size_t)(Bq + b) * PPq + Pq) * Sq;
    float4 rn2 = ((const float4*)wn1)[lane];
    float4 mh4 = ((const float4*)(mf + (size_t)Bq * Sq + b * Sq))[lane];
    float invLh = 1.f / fmaxf(lens[Bq + b], EPSq);

    float cmax[4] = {NEGB, NEGB, NEGB, NEGB};
    float csum[4] = {0.f, 0.f, 0.f, 0.f};
#pragma unroll
    for (int k = 0; k < 2; k++) {
        float r1 = wn0[i0 + k];
        float4 v;
        v.x = acc[k].x * r1 * rn2.x;
        v.y = acc[k].y * r1 * rn2.y;
        v.z = acc[k].z * r1 * rn2.z;
        v.w = acc[k].w * r1 * rn2.w;
        float m0 = mh4.x > 0.5f ? v.x : NEGB;
        float m1 = mh4.y > 0.5f ? v.y : NEGB;
        float m2 = mh4.z > 0.5f ? v.z : NEGB;
        float m3 = mh4.w > 0.5f ? v.w : NEGB;
        float rmax = fmaxf(fmaxf(m0, m1), fmaxf(m2, m3));
        float rs = v.x + v.y + v.z + v.w;
        for (int o = 32; o; o >>= 1) {
            rmax = fmaxf(rmax, __shfl_xor(rmax, o, 64));
            rs += __shfl_xor(rs, o, 64);
        }
        if (lane == 0) {
            float* orow = out + ((size_t)(b * Sq + i0 + k)) * Fq;
            orow[0] = rmax;
            orow[1] = rs * invLh;
        }
        float mi = mf[b * Sq + i0 + k];
        if (mi > 0.5f) {
            cmax[0] = fmaxf(cmax[0], v.x); cmax[1] = fmaxf(cmax[1], v.y);
            cmax[2] = fmaxf(cmax[2], v.z); cmax[3] = fmaxf(cmax[3], v.w);
        }
        csum[0] += v.x; csum[1] += v.y; csum[2] += v.z; csum[3] += v.w;
        ((float4*)(cosm + (size_t)(b * Sq + i0 + k) * Sq))[lane] = v;
        int jb = 4 * lane;
        cosT[((size_t)b * Sq + jb + 0) * Sq + i0 + k] = v.x;
        cosT[((size_t)b * Sq + jb + 1) * Sq + i0 + k] = v.y;
        cosT[((size_t)b * Sq + jb + 2) * Sq + i0 + k] = v.z;
        cosT[((size_t)b * Sq + jb + 3) * Sq + i0 + k] = v.w;
    }
    ((float4*)&cbmax[wid][0])[lane] = make_float4(cmax[0], cmax[1], cmax[2], cmax[3]);
    ((float4*)&cbsum[wid][0])[lane] = make_float4(csum[0], csum[1], csum[2], csum[3]);
    __syncthreads();
    {
        int j = t;
        float mx = fmaxf(fmaxf(cbmax[0][j], cbmax[1][j]), fmaxf(cbmax[2][j], cbmax[3][j]));
        float sm = cbsum[0][j] + cbsum[1][j] + cbsum[2][j] + cbsum[3][j];
        size_t cidx = ((size_t)b * PPq + Pq) * Sq + j;
        atomicMax(colmax + cidx, fkey(mx));
        atomicAdd(colsum + cidx, sm);
    }
}

// ---------------- k_attf: k_att + fused k_final (attn vectors stay in LDS) ----------------
// R18: REVERTED to the verified R10 version (Lw2 LDS table restored — R13's global-weight
// reads regressed 127.0 -> 133.7: the final phase is load-issue-bound, not occupancy-bound).
// grid 512 = (2 dir) x (8 b) x (32 row-tiles of 8 rows), 256 threads
__global__ __launch_bounds__(256) void k_attf(
    const float* __restrict__ vm, const float* __restrict__ mf,
    const float* __restrict__ cosm, const float* __restrict__ cosT,
    const unsigned* __restrict__ rowmax, const float* __restrict__ rowsum,
    const unsigned* __restrict__ colmax, const float* __restrict__ colsum,
    const float* __restrict__ lens, const int* __restrict__ lasts,
    const float* __restrict__ w_full, const float* __restrict__ w_att,
    const float* __restrict__ w_maxatt,
    float* __restrict__ out) {
    __shared__ float L[Sq * 8];          // [k][8 r]
    __shared__ float bm[Sq];
    __shared__ float pam[2][8][128];
    __shared__ float pax[2][8][128];
    __shared__ float Lw2[3 * Hq * 21];   // [m][h][p], slot p=20 holds 1.0 (plain cosine)
    __shared__ float Lv1[8 * 104];       // [r][h]  masked context rows (side d)
    __shared__ float Lam[8 * 104];       // [r][h]  attention-mean vectors
    __shared__ float Lax[8 * 104];       // [r][h]  attention-max  vectors
    __shared__ float Lv2u[104];          // last valid token of other side
    int blk = blockIdx.x;
    int t = threadIdx.x;
    int d = blk >> 8;
    int rem = blk & 255;
    int b = rem >> 5, rt = rem & 31;
    int r0 = rt * 8;

    if (blk < Bq * PPq) {            // col fold -> dir1 rows
        int bcf = blk / PPq, pcf = blk - bcf * PPq;
        float mx = funkey(colmax[(size_t)blk * Sq + t]);
        float sm = colsum[(size_t)blk * Sq + t];
        float invLp = 1.f / fmaxf(lens[bcf], EPSq);
        float* orow = out + (size_t)Bq * Sq * Fq + (size_t)(bcf * Sq + t) * Fq;
        if (pcf < Pq) { orow[23 + pcf] = mx; orow[43 + pcf] = sm * invLp; }
        else { orow[0] = mx; orow[1] = sm * invLp; }
    } else if (blk < 2 * Bq * PPq) { // row fold -> dir0 rows (p<20; p==20 by cos path)
        int rf = blk - Bq * PPq;
        int bcf = rf / PPq, pcf = rf - bcf * PPq;
        if (pcf < Pq) {
            float mx = funkey(rowmax[(size_t)(bcf * PPq + pcf) * Sq + t]);
            float sm = rowsum[(size_t)(bcf * PPq + pcf) * Sq + t];
            float invLh = 1.f / fmaxf(lens[Bq + bcf], EPSq);
            float* orow = out + (size_t)(bcf * Sq + t) * Fq;
            orow[23 + pcf] = mx; orow[43 + pcf] = sm * invLh;
        }
    }
    bm[t] = (mf[(size_t)(1 - d) * Bq * Sq + b * Sq + t] > 0.5f) ? 0.f : NEGB;

    // --- prologue loads for the fused final phase (independent, overlap with L staging) ---
    for (int idx = t; idx < 3 * Pq * Hq; idx += 256) {
        int m = idx / (Pq * Hq);
        int rem2 = idx - m * (Pq * Hq);
        int p = rem2 / Hq, h = rem2 - p * Hq;
        const float* W = (m == 0) ? w_full : (m == 1) ? w_att : w_maxatt;
        float w = W[p * Hq + h];
        Lw2[(m * Hq + h) * 21 + p] = w * w;
    }
    for (int idx = t; idx < 3 * Hq; idx += 256) {
        int m = idx / Hq, h = idx - m * Hq;
        Lw2[(m * Hq + h) * 21 + 20] = 1.f;      // plain-cosine slot
    }
    for (int idx = t; idx < 8 * Hq; idx += 256) {
        int r = idx / Hq, h = idx - r * Hq;
        Lv1[r * 104 + h] =
            vm[(size_t)d * Bq * Sq * Hq + ((size_t)b * Sq + r0 + r) * Hq + h];
    }
    if (t < Hq) {
        int lastO = d ? lasts[b] : lasts[Bq + b];
        Lv2u[t] = vm[(size_t)(1 - d) * Bq * Sq * Hq + ((size_t)b * Sq + lastO) * Hq + t];
    }

    const float* src = (d ? cosm : cosT) + (size_t)b * Sq * Sq;
#pragma unroll
    for (int q = 0; q < 2; q++) {
        int F = t + 256 * q;
        int k = F >> 1, c = F & 1;
        float4 v4 = *(const float4*)(src + (size_t)k * Sq + r0 + c * 4);
        *(float4*)(L + k * 8 + c * 4) = v4;
    }
    __syncthreads();

    int h = t & 127, kh = t >> 7;
    const float* vB = vm + (size_t)(1 - d) * Bq * Sq * Hq + (size_t)b * Sq * Hq + h;
    bool hv = (h < Hq);
    float am[8], ax[8];
#pragma unroll
    for (int r = 0; r < 8; r++) { am[r] = 0.f; ax[r] = NEGB; }
    int k0 = kh * 128;
#pragma unroll 16
    for (int kk = 0; kk < 128; kk++) {
        int k = k0 + kk;
        float v = hv ? vB[(size_t)k * Hq] : 0.f;
        float4 w0 = *(const float4*)(L + k * 8);
        float4 w1 = *(const float4*)(L + k * 8 + 4);
        float bk = bm[k];
        float wv[8] = {w0.x, w0.y, w0.z, w0.w, w1.x, w1.y, w1.z, w1.w};
#pragma unroll
        for (int r = 0; r < 8; r++) {
            float pr = wv[r] * v;
            am[r] += pr;
            ax[r] = fmaxf(ax[r], pr + bk);
        }
    }
#pragma unroll
    for (int r = 0; r < 8; r++) { pam[kh][r][h] = am[r]; pax[kh][r][h] = ax[r]; }
    __syncthreads();
    if (t < Hq) {
#pragma unroll
        for (int r = 0; r < 8; r++) {
            Lam[r * 104 + t] = pam[0][r][t] + pam[1][r][t];
            Lax[r * 104 + t] = fmaxf(pax[0][r][t], pax[1][r][t]);
        }
    }
    __syncthreads();

    // --- fused k_final phase: 504 tasks = 8 rows x 3 matchers x 21 (20 persp + plain) ---
    size_t orow_base = (size_t)d * Bq * Sq * Fq + ((size_t)b * Sq + r0) * Fq;
    for (int task = t; task < 504; task += 256) {
        int r = task & 7;
        int mp = task >> 3;              // 0..62
        int m = mp / 21, p = mp - m * 21;
        const float* v1p = Lv1 + r * 104;
        const float* v2p = (m == 0) ? Lv2u : (m == 1 ? Lam + r * 104 : Lax + r * 104);
        const float* wp = Lw2 + m * Hq * 21 + p;
        float dd = 0.f, aa = 0.f, bb = 0.f;
#pragma unroll 4
        for (int hh = 0; hh < Hq; hh++) {
            float v1 = v1p[hh], v2 = v2p[hh], w = wp[hh * 21];
            dd += w * v1 * v2; aa += w * v1 * v1; bb += w * v2 * v2;
        }
        int fbase = (m == 0) ? 2 : (m == 1) ? 63 : 84;
        int col = (p < 20) ? (fbase + 1 + p) : fbase;
        out[orow_base + (size_t)r * Fq + col] =
            dd / (fmaxf(sqrtf(aa), EPSq) * fmaxf(sqrtf(bb), EPSq));
    }
}

extern "C" void kernel_launch(void* const* d_in, const int* in_sizes, int n_in,
                              void* d_out, int out_size, void* d_ws, size_t ws_size,
                              hipStream_t stream) {
    (void)in_sizes; (void)n_in; (void)out_size; (void)ws_size;
    const float* ctx_p    = (const float*)d_in[0];
    const int*   mask_p   = (const int*)d_in[1];
    const float* ctx_h    = (const float*)d_in[2];
    const int*   mask_h   = (const int*)d_in[3];
    const float* w_full   = (const float*)d_in[4];
    const float* w_maxpool= (const float*)d_in[5];
    const float* w_att    = (const float*)d_in[6];
    const float* w_maxatt = (const float*)d_in[7];
    float* out = (float*)d_out;
    float* ws = (float*)d_ws;

    const size_t BSH = (size_t)Bq * Sq * Hq;
    const size_t BS  = (size_t)Bq * Sq;
    const size_t BSS = (size_t)Bq * Sq * Sq;
    const size_t BPS = (size_t)Bq * PPq * Sq;

    float* vm     = ws;               ws += 2 * BSH;
    float* vmT    = ws;               ws += 2 * BSH;
    unsigned short* a16 = (unsigned short*)ws;  ws += 2 * Bq * IMG / 2 * 2;  // 2*8*2*IMG shorts
    float* mf     = ws;               ws += 2 * BS;
    float* wn     = ws;               ws += 2 * BPS;
    float* cosm   = ws;               ws += BSS;
    float* cosT   = ws;               ws += BSS;
    unsigned* rowmax = (unsigned*)ws; ws += BPS;
    float* rowsum = ws;               ws += BPS;
    unsigned* colmax = (unsigned*)ws; ws += BPS;
    float* colsum = ws;               ws += BPS;   // row/col stat bufs contiguous (one zero pass)
    float* lens   = ws;               ws += 16;
    int*   lasts  = (int*)ws;         ws += 16;

    k_prep<<<256, 256, 0, stream>>>(ctx_p, mask_p, ctx_h, mask_h, w_maxpool,
                                    vm, vmT, mf, wn, a16, lens, lasts, rowmax);
    k_pw<<<896, 256, 0, stream>>>(a16, vmT, wn, mf, w_maxpool, lens,
                                  out, cosm, cosT, rowmax, rowsum, colmax, colsum);
    k_attf<<<512, 256, 0, stream>>>(vm, mf, cosm, cosT, rowmax, rowsum, colmax, colsum,
                                    lens, lasts, w_full, w_att, w_maxatt, out);
}

// Round 20
// 126.985 us; speedup vs baseline: 1.0531x; 1.0143x over previous
//
#include <hip/hip_runtime.h>

#define Bq 8
#define Sq 256
#define Hq 100
#define Pq 20
#define PPq 21
#define Fq 105
#define EPSq 1e-8f
#define NEGB -1e30f
#define IMG (128 * 136)   // padded bf16 operand image: 128 rows x 136 shorts (272 B)

typedef short bf16x8 __attribute__((ext_vector_type(8)));
typedef float f32x4 __attribute__((ext_vector_type(4)));

__device__ __forceinline__ unsigned fkey(float f) {
    unsigned b = __float_as_uint(f);
    return (b & 0x80000000u) ? ~b : (b | 0x80000000u);
}
__device__ __forceinline__ float funkey(unsigned k) {
    return __uint_as_float((k & 0x80000000u) ? (k ^ 0x80000000u) : ~k);
}
__device__ __forceinline__ unsigned short bf16rn(float f) {
    unsigned u = __float_as_uint(f);
    unsigned r = u + 0x7FFFu + ((u >> 16) & 1u);
    return (unsigned short)(r >> 16);
}
__device__ __forceinline__ unsigned mulpack(unsigned pair, float w0, float w1) {
    float f0 = __uint_as_float(pair << 16);
    float f1 = __uint_as_float(pair & 0xFFFF0000u);
    f0 *= w0; f1 *= w1;
    return ((unsigned)bf16rn(f0)) | (((unsigned)bf16rn(f1)) << 16);
}

// ---------------- k_prep: 256 blocks = (side, b, 16-token sixteenth) ----------------------
__global__ __launch_bounds__(256) void k_prep(
    const float* __restrict__ ctx_p, const int* __restrict__ mask_p,
    const float* __restrict__ ctx_h, const int* __restrict__ mask_h,
    const float* __restrict__ w_mp,
    float* __restrict__ vm, float* __restrict__ vmT,
    float* __restrict__ mf, float* __restrict__ wn,
    unsigned short* __restrict__ a16,   // [2 side][B][2 half][IMG]
    float* __restrict__ lens, int* __restrict__ lasts,
    unsigned* __restrict__ statinit) {  // 4*B*PP*S words to zero
    __shared__ float tileT[Hq * 17];    // [h][s_local 16], stride-17 pad
    __shared__ float w2T[Hq * 20];      // [h][p]
    __shared__ float redp[PPq * 4 * 16];// [p][hq][sl]
    __shared__ float smf[16];
    __shared__ int ired[256];
    int blk = blockIdx.x;
    int side = blk >> 7;
    int b = (blk >> 4) & 7;
    int sq = blk & 15;
    int s0 = sq * 16;
    int t = threadIdx.x;

    for (int idx = blk * 256 + t; idx < 4 * Bq * PPq * Sq; idx += 256 * 256)
        statinit[idx] = 0u;

    const float* ctx = side ? ctx_h : ctx_p;
    const int* mask = side ? mask_h : mask_p;
    ired[t] = mask[b * Sq + t];
    if (t < 16) smf[t] = (float)mask[b * Sq + s0 + t];
    for (int idx = t; idx < Pq * Hq; idx += 256) {
        int p = idx / Hq, h = idx - p * Hq;
        float w = w_mp[idx];
        w2T[h * 20 + p] = w * w;
    }
    __syncthreads();
    if (sq == 0) {                      // block-uniform branch: syncthreads legal
        for (int o = 128; o; o >>= 1) {
            if (t < o) ired[t] += ired[t + o];
            __syncthreads();
        }
        if (t == 0) {
            int l = ired[0];
            lens[side * Bq + b] = (float)l;
            lasts[side * Bq + b] = l > 0 ? l - 1 : 0;
        }
    }

    unsigned short* abase = a16 + (size_t)(side * Bq + b) * 2 * IMG;
    // zero pad region h in [100,136) for this block's 16 rows
    {
        ushort4 z = {0, 0, 0, 0};
        for (int idx = t; idx < 144; idx += 256) {
            int r = idx / 9, c = idx - r * 9;
            int g = s0 + r;
            *(ushort4*)(abase + (g >> 7) * IMG + (g & 127) * 136 + 100 + c * 4) = z;
        }
    }

    const float4* src = (const float4*)(ctx + ((size_t)b * Sq + s0) * Hq);
    float4* vmo = (float4*)(vm + ((size_t)side * Bq + b) * Sq * Hq + (size_t)s0 * Hq);
#pragma unroll
    for (int q = 0; q < 2; q++) {
        int F = t + 256 * q;
        if (F < 400) {                  // 16 rows x 25 float4
            int s = F / 25, c = F - s * 25;
            float m = smf[s];
            float4 v4 = src[F];
            v4.x *= m; v4.y *= m; v4.z *= m; v4.w *= m;
            vmo[F] = v4;
            int h0 = c * 4;
            tileT[(h0 + 0) * 17 + s] = v4.x;
            tileT[(h0 + 1) * 17 + s] = v4.y;
            tileT[(h0 + 2) * 17 + s] = v4.z;
            tileT[(h0 + 3) * 17 + s] = v4.w;
            int g = s0 + s;
            ushort4 o;
            o.x = bf16rn(v4.x); o.y = bf16rn(v4.y); o.z = bf16rn(v4.z); o.w = bf16rn(v4.w);
            *(ushort4*)(abase + (g >> 7) * IMG + (g & 127) * 136 + c * 4) = o;
        }
    }
    __syncthreads();

    if (t < 64) {                       // 16 tokens x 4 h-groups of 25 (order as before)
        int sl = t & 15, hq = t >> 4;
        float acc[PPq];
#pragma unroll
        for (int p = 0; p < PPq; p++) acc[p] = 0.f;
        float* vmTo = vmT + ((size_t)side * Bq + b) * Hq * Sq + s0;
        int hbeg = hq * 25;
#pragma unroll 5
        for (int h = hbeg; h < hbeg + 25; h++) {
            float v = tileT[h * 17 + sl];
            vmTo[(size_t)h * Sq + sl] = v;
            float e = v * v;
            acc[Pq] += e;
            const float4* wrow = (const float4*)(w2T + h * 20);
#pragma unroll
            for (int pq = 0; pq < 5; pq++) {
                float4 w4 = wrow[pq];
                acc[pq * 4 + 0] += w4.x * e;
                acc[pq * 4 + 1] += w4.y * e;
                acc[pq * 4 + 2] += w4.z * e;
                acc[pq * 4 + 3] += w4.w * e;
            }
        }
#pragma unroll
        for (int p = 0; p < PPq; p++)
            redp[(p * 4 + hq) * 16 + sl] = acc[p];
    }
    __syncthreads();

    float* wout = wn + ((size_t)side * Bq + b) * PPq * Sq + s0;
    for (int idx = t; idx < PPq * 16; idx += 256) {
        int p = idx >> 4, s2 = idx & 15;
        float ssum = redp[(p * 4 + 0) * 16 + s2] + redp[(p * 4 + 1) * 16 + s2] +
                     redp[(p * 4 + 2) * 16 + s2] + redp[(p * 4 + 3) * 16 + s2];
        wout[p * Sq + s2] = 1.f / fmaxf(sqrtf(ssum), EPSq);
    }
    if (t < 16) mf[(size_t)side * Bq * Sq + b * Sq + s0 + t] = smf[t];
}

// ---------------- k_pw: blocks 0..63 = exact-f32 plain cosine (runs first);
//   blocks 64..703 = bf16 MFMA weighted perspectives.
//   R8: A-fragments read DIRECTLY from global a16 (L2-hot, 40x reuse) — A LDS staging
//   deleted; B staged once for both K-chunks -> 1 barrier/block instead of 4. ------------
__global__ __launch_bounds__(256) void k_pw(
    const unsigned short* __restrict__ a16,
    const float* __restrict__ vmT,
    const float* __restrict__ wn, const float* __restrict__ mf,
    const float* __restrict__ w_mp, const float* __restrict__ lens,
    float* __restrict__ out, float* __restrict__ cosm, float* __restrict__ cosT,
    unsigned* __restrict__ rowmax, float* __restrict__ rowsum,
    unsigned* __restrict__ colmax, float* __restrict__ colsum) {
    __shared__ unsigned short Bs[2 * 128 * 72]; // [q][j][h-chunk] bf16 of w^2*b (36.9 KB)
    __shared__ float w2s[144];
    int blk = blockIdx.x;
    int t = threadIdx.x;

    if (blk >= 64) {
        // ---------------- MFMA path ----------------
        int mblk = blk - 64;
        int b = mblk / 80;
        int rem = mblk - b * 80;
        int p = rem >> 2;
        int ih = (rem >> 1) & 1, jh = rem & 1;
        int i0 = ih * 128, j0 = jh * 128;

        if (t < 144) {
            float w = (t < Hq) ? w_mp[p * Hq + t] : 0.f;
            w2s[t] = w * w;
        }
        __syncthreads();

        const unsigned short* ag = a16 + (size_t)(b * 2 + ih) * IMG;     // A half-image
        const uint4* sb = (const uint4*)(a16 + (size_t)((Bq + b) * 2 + jh) * IMG);
        uint4* dB = (uint4*)Bs;

        int lane = t & 63;
        int wv = t >> 6;
        int wr = wv & 1, wc = wv >> 1;
        int lm = lane & 15, lq = lane >> 4;

        f32x4 acc[4][4];
#pragma unroll
        for (int tm = 0; tm < 4; tm++)
#pragma unroll
            for (int tn = 0; tn < 4; tn++) acc[tm][tn] = 0.f;

        // stage BOTH B K-chunks (2048 uint4), one barrier total
#pragma unroll
        for (int it = 0; it < 8; it++) {
            int idx = t + 256 * it;              // 0..2047
            int q = idx >> 10, rem2 = idx & 1023;
            int row = rem2 >> 3, cc = rem2 & 7;
            int hb = (q * 8 + cc) * 8;
            uint4 ch = sb[row * 17 + q * 8 + cc];
            float4 wA = *(const float4*)(w2s + hb);
            float4 wB = *(const float4*)(w2s + hb + 4);
            uint4 o;
            o.x = mulpack(ch.x, wA.x, wA.y);
            o.y = mulpack(ch.y, wA.z, wA.w);
            o.z = mulpack(ch.z, wB.x, wB.y);
            o.w = mulpack(ch.w, wB.z, wB.w);
            dB[q * 1152 + row * 9 + cc] = o;
        }
        __syncthreads();

#pragma unroll
        for (int q = 0; q < 2; q++)
#pragma unroll
            for (int ksl = 0; ksl < 2; ksl++) {
                bf16x8 af[4], bfr[4];
#pragma unroll
                for (int tm = 0; tm < 4; tm++)
                    af[tm] = *(const bf16x8*)&ag[(wr * 64 + tm * 16 + lm) * 136 + q * 64 + ksl * 32 + lq * 8];
#pragma unroll
                for (int tn = 0; tn < 4; tn++)
                    bfr[tn] = *(const bf16x8*)&Bs[q * 9216 + (wc * 64 + tn * 16 + lm) * 72 + ksl * 32 + lq * 8];
#pragma unroll
                for (int tm = 0; tm < 4; tm++)
#pragma unroll
                    for (int tn = 0; tn < 4; tn++)
                        acc[tm][tn] = __builtin_amdgcn_mfma_f32_16x16x32_bf16(af[tm], bfr[tn], acc[tm][tn], 0, 0, 0);
            }

        const float* wn0 = wn + ((size_t)b * PPq + p) * Sq;
        const float* wn1 = wn + ((size_t)(Bq + b) * PPq + p) * Sq;
        const float* mfp = mf + b * Sq;
        const float* mfh = mf + (size_t)Bq * Sq + b * Sq;
        size_t base = ((size_t)b * PPq + p) * Sq;
        float rn2v[4], mzh[4];
#pragma unroll
        for (int tn = 0; tn < 4; tn++) {
            int jj = j0 + wc * 64 + tn * 16 + lm;
            rn2v[tn] = wn1[jj];
            mzh[tn] = mfh[jj] > 0.5f ? 0.f : NEGB;
        }
        float cmax[4] = {NEGB, NEGB, NEGB, NEGB};
        float csum[4] = {0.f, 0.f, 0.f, 0.f};
#pragma unroll
        for (int tm = 0; tm < 4; tm++) {
            int ibase = i0 + wr * 64 + tm * 16 + lq * 4;
            float rn1v[4], mzp[4];
#pragma unroll
            for (int r2 = 0; r2 < 4; r2++) {
                rn1v[r2] = wn0[ibase + r2];
                mzp[r2] = mfp[ibase + r2] > 0.5f ? 0.f : NEGB;
            }
            float rmax[4] = {NEGB, NEGB, NEGB, NEGB};
            float rsum[4] = {0.f, 0.f, 0.f, 0.f};
#pragma unroll
            for (int tn = 0; tn < 4; tn++)
#pragma unroll
                for (int r2 = 0; r2 < 4; r2++) {
                    float v = acc[tm][tn][r2] * rn1v[r2] * rn2v[tn];
                    rmax[r2] = fmaxf(rmax[r2], v + mzh[tn]);
                    rsum[r2] += v;
                    cmax[tn] = fmaxf(cmax[tn], v + mzp[r2]);
                    csum[tn] += v;
                }
#pragma unroll
            for (int r2 = 0; r2 < 4; r2++)
#pragma unroll
                for (int o = 1; o < 16; o <<= 1) {
                    rmax[r2] = fmaxf(rmax[r2], __shfl_xor(rmax[r2], o, 64));
                    rsum[r2] += __shfl_xor(rsum[r2], o, 64);
                }
            if (lm == 0) {
#pragma unroll
                for (int r2 = 0; r2 < 4; r2++) {
                    atomicMax(rowmax + base + ibase + r2, fkey(rmax[r2]));
                    atomicAdd(rowsum + base + ibase + r2, rsum[r2]);
                }
            }
        }
#pragma unroll
        for (int tn = 0; tn < 4; tn++) {
#pragma unroll
            for (int o = 16; o < 64; o <<= 1) {
                cmax[tn] = fmaxf(cmax[tn], __shfl_xor(cmax[tn], o, 64));
                csum[tn] += __shfl_xor(csum[tn], o, 64);
            }
        }
        if (lq == 0) {
#pragma unroll
            for (int tn = 0; tn < 4; tn++) {
                int jj = j0 + wc * 64 + tn * 16 + lm;
                atomicMax(colmax + base + jj, fkey(cmax[tn]));
                atomicAdd(colsum + base + jj, csum[tn]);
            }
        }
        return;
    }

    // ---------------- exact-f32 plain cosine path (p == 20), blocks 0..63 ----------------
    float (*cbmax)[Sq] = (float (*)[Sq])Bs;             // 0..4 KB of Bs
    float (*cbsum)[Sq] = (float (*)[Sq])(Bs + 4096);    // 8..12 KB of Bs (within 36.9 KB)
    int b = blk >> 3, it = blk & 7;
    int lane = t & 63;
    int wid = __builtin_amdgcn_readfirstlane(t >> 6);
    int i0 = it * 32 + wid * 8;

    const float* abase2 = vmT + (size_t)b * Hq * Sq;
    const float* bbase2 = vmT + (size_t)(Bq + b) * Hq * Sq;

    float4 acc[8];
#pragma unroll
    for (int k = 0; k < 8; k++) acc[k] = make_float4(0.f, 0.f, 0.f, 0.f);

#pragma unroll 4
    for (int h = 0; h < Hq; h++) {
        float4 bq = ((const float4*)(bbase2 + h * Sq))[lane];
        const float4* ap = (const float4*)(abase2 + h * Sq + i0);
        float4 a0 = ap[0], a1 = ap[1];
        float av[8] = {a0.x, a0.y, a0.z, a0.w, a1.x, a1.y, a1.z, a1.w};
#pragma unroll
        for (int k = 0; k < 8; k++) {
            acc[k].x += av[k] * bq.x; acc[k].y += av[k] * bq.y;
            acc[k].z += av[k] * bq.z; acc[k].w += av[k] * bq.w;
        }
    }

    const float* wn0 = wn + ((size_t)b * PPq + Pq) * Sq;
    const float* wn1 = wn + ((size_t)(Bq + b) * PPq + Pq) * Sq;
    float4 rn2 = ((const float4*)wn1)[lane];
    float4 mh4 = ((const float4*)(mf + (size_t)Bq * Sq + b * Sq))[lane];
    float invLh = 1.f / fmaxf(lens[Bq + b], EPSq);

    float cmax[4] = {NEGB, NEGB, NEGB, NEGB};
    float csum[4] = {0.f, 0.f, 0.f, 0.f};
#pragma unroll
    for (int k = 0; k < 8; k++) {
        float r1 = wn0[i0 + k];
        float4 v;
        v.x = acc[k].x * r1 * rn2.x;
        v.y = acc[k].y * r1 * rn2.y;
        v.z = acc[k].z * r1 * rn2.z;
        v.w = acc[k].w * r1 * rn2.w;
        float m0 = mh4.x > 0.5f ? v.x : NEGB;
        float m1 = mh4.y > 0.5f ? v.y : NEGB;
        float m2 = mh4.z > 0.5f ? v.z : NEGB;
        float m3 = mh4.w > 0.5f ? v.w : NEGB;
        float rmax = fmaxf(fmaxf(m0, m1), fmaxf(m2, m3));
        float rs = v.x + v.y + v.z + v.w;
        for (int o = 32; o; o >>= 1) {
            rmax = fmaxf(rmax, __shfl_xor(rmax, o, 64));
            rs += __shfl_xor(rs, o, 64);
        }
        if (lane == 0) {
            float* orow = out + ((size_t)(b * Sq + i0 + k)) * Fq;
            orow[0] = rmax;
            orow[1] = rs * invLh;
        }
        float mi = mf[b * Sq + i0 + k];
        if (mi > 0.5f) {
            cmax[0] = fmaxf(cmax[0], v.x); cmax[1] = fmaxf(cmax[1], v.y);
            cmax[2] = fmaxf(cmax[2], v.z); cmax[3] = fmaxf(cmax[3], v.w);
        }
        csum[0] += v.x; csum[1] += v.y; csum[2] += v.z; csum[3] += v.w;
        ((float4*)(cosm + (size_t)(b * Sq + i0 + k) * Sq))[lane] = v;
        int jb = 4 * lane;
        cosT[((size_t)b * Sq + jb + 0) * Sq + i0 + k] = v.x;
        cosT[((size_t)b * Sq + jb + 1) * Sq + i0 + k] = v.y;
        cosT[((size_t)b * Sq + jb + 2) * Sq + i0 + k] = v.z;
        cosT[((size_t)b * Sq + jb + 3) * Sq + i0 + k] = v.w;
    }
    ((float4*)&cbmax[wid][0])[lane] = make_float4(cmax[0], cmax[1], cmax[2], cmax[3]);
    ((float4*)&cbsum[wid][0])[lane] = make_float4(csum[0], csum[1], csum[2], csum[3]);
    __syncthreads();
    {
        int j = t;
        float mx = fmaxf(fmaxf(cbmax[0][j], cbmax[1][j]), fmaxf(cbmax[2][j], cbmax[3][j]));
        float sm = cbsum[0][j] + cbsum[1][j] + cbsum[2][j] + cbsum[3][j];
        size_t cidx = ((size_t)b * PPq + Pq) * Sq + j;
        atomicMax(colmax + cidx, fkey(mx));
        atomicAdd(colsum + cidx, sm);
    }
}

// ---------------- k_attf: k_att + fused k_final (attn vectors stay in LDS) ----------------
// grid 512 = (2 dir) x (8 b) x (32 row-tiles of 8 rows), 256 threads
__global__ __launch_bounds__(256) void k_attf(
    const float* __restrict__ vm, const float* __restrict__ mf,
    const float* __restrict__ cosm, const float* __restrict__ cosT,
    const unsigned* __restrict__ rowmax, const float* __restrict__ rowsum,
    const unsigned* __restrict__ colmax, const float* __restrict__ colsum,
    const float* __restrict__ lens, const int* __restrict__ lasts,
    const float* __restrict__ w_full, const float* __restrict__ w_att,
    const float* __restrict__ w_maxatt,
    float* __restrict__ out) {
    __shared__ float L[Sq * 8];          // [k][8 r]
    __shared__ float bm[Sq];
    __shared__ float pam[2][8][128];
    __shared__ float pax[2][8][128];
    __shared__ float Lw2[3 * Hq * 21];   // [m][h][p], slot p=20 holds 1.0 (plain cosine)
    __shared__ float Lv1[8 * 104];       // [r][h]  masked context rows (side d)
    __shared__ float Lam[8 * 104];       // [r][h]  attention-mean vectors
    __shared__ float Lax[8 * 104];       // [r][h]  attention-max  vectors
    __shared__ float Lv2u[104];          // last valid token of other side
    int blk = blockIdx.x;
    int t = threadIdx.x;
    int d = blk >> 8;
    int rem = blk & 255;
    int b = rem >> 5, rt = rem & 31;
    int r0 = rt * 8;

    if (blk < Bq * PPq) {            // col fold -> dir1 rows
        int bcf = blk / PPq, pcf = blk - bcf * PPq;
        float mx = funkey(colmax[(size_t)blk * Sq + t]);
        float sm = colsum[(size_t)blk * Sq + t];
        float invLp = 1.f / fmaxf(lens[bcf], EPSq);
        float* orow = out + (size_t)Bq * Sq * Fq + (size_t)(bcf * Sq + t) * Fq;
        if (pcf < Pq) { orow[23 + pcf] = mx; orow[43 + pcf] = sm * invLp; }
        else { orow[0] = mx; orow[1] = sm * invLp; }
    } else if (blk < 2 * Bq * PPq) { // row fold -> dir0 rows (p<20; p==20 by cos path)
        int rf = blk - Bq * PPq;
        int bcf = rf / PPq, pcf = rf - bcf * PPq;
        if (pcf < Pq) {
            float mx = funkey(rowmax[(size_t)(bcf * PPq + pcf) * Sq + t]);
            float sm = rowsum[(size_t)(bcf * PPq + pcf) * Sq + t];
            float invLh = 1.f / fmaxf(lens[Bq + bcf], EPSq);
            float* orow = out + (size_t)(bcf * Sq + t) * Fq;
            orow[23 + pcf] = mx; orow[43 + pcf] = sm * invLh;
        }
    }
    bm[t] = (mf[(size_t)(1 - d) * Bq * Sq + b * Sq + t] > 0.5f) ? 0.f : NEGB;

    // --- prologue loads for the fused final phase (independent, overlap with L staging) ---
    for (int idx = t; idx < 3 * Pq * Hq; idx += 256) {
        int m = idx / (Pq * Hq);
        int rem2 = idx - m * (Pq * Hq);
        int p = rem2 / Hq, h = rem2 - p * Hq;
        const float* W = (m == 0) ? w_full : (m == 1) ? w_att : w_maxatt;
        float w = W[p * Hq + h];
        Lw2[(m * Hq + h) * 21 + p] = w * w;
    }
    for (int idx = t; idx < 3 * Hq; idx += 256) {
        int m = idx / Hq, h = idx - m * Hq;
        Lw2[(m * Hq + h) * 21 + 20] = 1.f;      // plain-cosine slot
    }
    for (int idx = t; idx < 8 * Hq; idx += 256) {
        int r = idx / Hq, h = idx - r * Hq;
        Lv1[r * 104 + h] =
            vm[(size_t)d * Bq * Sq * Hq + ((size_t)b * Sq + r0 + r) * Hq + h];
    }
    if (t < Hq) {
        int lastO = d ? lasts[b] : lasts[Bq + b];
        Lv2u[t] = vm[(size_t)(1 - d) * Bq * Sq * Hq + ((size_t)b * Sq + lastO) * Hq + t];
    }

    const float* src = (d ? cosm : cosT) + (size_t)b * Sq * Sq;
#pragma unroll
    for (int q = 0; q < 2; q++) {
        int F = t + 256 * q;
        int k = F >> 1, c = F & 1;
        float4 v4 = *(const float4*)(src + (size_t)k * Sq + r0 + c * 4);
        *(float4*)(L + k * 8 + c * 4) = v4;
    }
    __syncthreads();

    int h = t & 127, kh = t >> 7;
    const float* vB = vm + (size_t)(1 - d) * Bq * Sq * Hq + (size_t)b * Sq * Hq + h;
    bool hv = (h < Hq);
    float am[8], ax[8];
#pragma unroll
    for (int r = 0; r < 8; r++) { am[r] = 0.f; ax[r] = NEGB; }
    int k0 = kh * 128;
#pragma unroll 16
    for (int kk = 0; kk < 128; kk++) {
        int k = k0 + kk;
        float v = hv ? vB[(size_t)k * Hq] : 0.f;
        float4 w0 = *(const float4*)(L + k * 8);
        float4 w1 = *(const float4*)(L + k * 8 + 4);
        float bk = bm[k];
        float wv[8] = {w0.x, w0.y, w0.z, w0.w, w1.x, w1.y, w1.z, w1.w};
#pragma unroll
        for (int r = 0; r < 8; r++) {
            float pr = wv[r] * v;
            am[r] += pr;
            ax[r] = fmaxf(ax[r], pr + bk);
        }
    }
#pragma unroll
    for (int r = 0; r < 8; r++) { pam[kh][r][h] = am[r]; pax[kh][r][h] = ax[r]; }
    __syncthreads();
    if (t < Hq) {
#pragma unroll
        for (int r = 0; r < 8; r++) {
            Lam[r * 104 + t] = pam[0][r][t] + pam[1][r][t];
            Lax[r * 104 + t] = fmaxf(pax[0][r][t], pax[1][r][t]);
        }
    }
    __syncthreads();

    // --- fused k_final phase: 504 tasks = 8 rows x 3 matchers x 21 (20 persp + plain) ---
    size_t orow_base = (size_t)d * Bq * Sq * Fq + ((size_t)b * Sq + r0) * Fq;
    for (int task = t; task < 504; task += 256) {
        int r = task & 7;
        int mp = task >> 3;              // 0..62
        int m = mp / 21, p = mp - m * 21;
        const float* v1p = Lv1 + r * 104;
        const float* v2p = (m == 0) ? Lv2u : (m == 1 ? Lam + r * 104 : Lax + r * 104);
        const float* wp = Lw2 + m * Hq * 21 + p;
        float dd = 0.f, aa = 0.f, bb = 0.f;
#pragma unroll 4
        for (int hh = 0; hh < Hq; hh++) {
            float v1 = v1p[hh], v2 = v2p[hh], w = wp[hh * 21];
            dd += w * v1 * v2; aa += w * v1 * v1; bb += w * v2 * v2;
        }
        int fbase = (m == 0) ? 2 : (m == 1) ? 63 : 84;
        int col = (p < 20) ? (fbase + 1 + p) : fbase;
        out[orow_base + (size_t)r * Fq + col] =
            dd / (fmaxf(sqrtf(aa), EPSq) * fmaxf(sqrtf(bb), EPSq));
    }
}

extern "C" void kernel_launch(void* const* d_in, const int* in_sizes, int n_in,
                              void* d_out, int out_size, void* d_ws, size_t ws_size,
                              hipStream_t stream) {
    (void)in_sizes; (void)n_in; (void)out_size; (void)ws_size;
    const float* ctx_p    = (const float*)d_in[0];
    const int*   mask_p   = (const int*)d_in[1];
    const float* ctx_h    = (const float*)d_in[2];
    const int*   mask_h   = (const int*)d_in[3];
    const float* w_full   = (const float*)d_in[4];
    const float* w_maxpool= (const float*)d_in[5];
    const float* w_att    = (const float*)d_in[6];
    const float* w_maxatt = (const float*)d_in[7];
    float* out = (float*)d_out;
    float* ws = (float*)d_ws;

    const size_t BSH = (size_t)Bq * Sq * Hq;
    const size_t BS  = (size_t)Bq * Sq;
    const size_t BSS = (size_t)Bq * Sq * Sq;
    const size_t BPS = (size_t)Bq * PPq * Sq;

    float* vm     = ws;               ws += 2 * BSH;
    float* vmT    = ws;               ws += 2 * BSH;
    unsigned short* a16 = (unsigned short*)ws;  ws += 2 * Bq * IMG / 2 * 2;  // 2*8*2*IMG shorts
    float* mf     = ws;               ws += 2 * BS;
    float* wn     = ws;               ws += 2 * BPS;
    float* cosm   = ws;               ws += BSS;
    float* cosT   = ws;               ws += BSS;
    unsigned* rowmax = (unsigned*)ws; ws += BPS;
    float* rowsum = ws;               ws += BPS;
    unsigned* colmax = (unsigned*)ws; ws += BPS;
    float* colsum = ws;               ws += BPS;   // row/col stat bufs contiguous (one zero pass)
    float* lens   = ws;               ws += 16;
    int*   lasts  = (int*)ws;         ws += 16;

    k_prep<<<256, 256, 0, stream>>>(ctx_p, mask_p, ctx_h, mask_h, w_maxpool,
                                    vm, vmT, mf, wn, a16, lens, lasts, rowmax);
    k_pw<<<704, 256, 0, stream>>>(a16, vmT, wn, mf, w_maxpool, lens,
                                  out, cosm, cosT, rowmax, rowsum, colmax, colsum);
    k_attf<<<512, 256, 0, stream>>>(vm, mf, cosm, cosT, rowmax, rowsum, colmax, colsum,
                                    lens, lasts, w_full, w_att, w_maxatt, out);
}